// Round 1
// baseline (222.984 us; speedup 1.0000x reference)
//
#include <hip/hip_runtime.h>
#include <cstdint>
#include <cstddef>

// LSTM cell: B=4096, IN=1024, H=1024
//   ifgo = h @ Wh^T + bh + x @ Wx^T    [4096 x 4096]
//   i,f,g,o = split(ifgo); c' = sig(f)*c + sig(i)*tanh(g); h' = sig(o)*tanh(c')
// Pipeline: fp32->bf16 convert -> bf16 MFMA GEMM (m97 structure) -> gate epilogue.

#define NB   4096      // batch
#define KH   1024      // H (== IN)
#define NOUT 4096      // 4H
#define ARR_ELEMS 4194304  // 4096*1024

typedef __bf16 bf16x8 __attribute__((ext_vector_type(8)));
typedef float  f32x4  __attribute__((ext_vector_type(4)));

__device__ inline unsigned short f2bf(float f) {
    union { float f; unsigned int u; } v; v.f = f;
    unsigned int u = v.u;
    u += 0x7FFFu + ((u >> 16) & 1u);   // RNE
    return (unsigned short)(u >> 16);
}
__device__ inline float bf2f(unsigned short s) {
    union { unsigned int u; float f; } v; v.u = ((unsigned int)s) << 16;
    return v.f;
}

// ---------------------------------------------------------------- convert ---
// dst layout (bf16): [h | x | Wh | Wx], each ARR_ELEMS elements.
__global__ void convert_kernel(const float* __restrict__ h, const float* __restrict__ x,
                               const float* __restrict__ Wh, const float* __restrict__ Wx,
                               unsigned short* __restrict__ dst) {
    int idx = blockIdx.x * 256 + threadIdx.x;       // 0 .. 4M-1, 4 floats each
    int arr = idx >> 20;                            // 2^20 float4-chunks per array
    int off = (idx & 0xFFFFF) << 2;
    const float* src = (arr == 0) ? h : (arr == 1) ? x : (arr == 2) ? Wh : Wx;
    float4 v = *(const float4*)(src + off);
    unsigned int lo = (unsigned int)f2bf(v.x) | ((unsigned int)f2bf(v.y) << 16);
    unsigned int hi = (unsigned int)f2bf(v.z) | ((unsigned int)f2bf(v.w) << 16);
    uint2 packed; packed.x = lo; packed.y = hi;
    *(uint2*)(dst + (size_t)arr * ARR_ELEMS + off) = packed;
}

// ------------------------------------------------------------------- gemm ---
// C[4096x4096] = A_cat[4096x2048] . W_cat^T, A_cat = [h|x], W_cat = [Wh|Wx].
// 128x128 tile, BK=32, 256 threads (4 waves), each wave 64x64 via 4x4 MFMA
// 16x16x32 bf16. Staging via global_load_lds width=16.
__global__ void gemm_kernel(const unsigned short* __restrict__ Ah,
                            const unsigned short* __restrict__ Ax,
                            const unsigned short* __restrict__ Bh,
                            const unsigned short* __restrict__ Bx,
                            unsigned short* __restrict__ C) {
    __shared__ __align__(16) unsigned short As[128 * 32];
    __shared__ __align__(16) unsigned short Bs[128 * 32];

    const int tid  = threadIdx.x;
    const int wave = tid >> 6;
    const int lane = tid & 63;
    const int tileN = blockIdx.x;   // 0..31  (output cols / 128)
    const int tileM = blockIdx.y;   // 0..31  (output rows / 128)

    // staging addressing: chunk = wave*64 + lane (+256 for issue 1)
    // row(chunk) = chunk>>2, colchunk = chunk&3 (8 bf16 = 16B per chunk)
    const int stRow  = wave * 16 + (lane >> 2);   // 0..63 for issue 0
    const int stColE = (lane & 3) * 8;            // element offset in K
    const size_t gaRow = (size_t)(tileM * 128 + stRow) * KH;
    const size_t gbRow = (size_t)(tileN * 128 + stRow) * KH;

    // compute-side fragment addressing
    const int mBase = (wave >> 1) * 64;
    const int nBase = (wave & 1) * 64;
    const int fr = lane & 15;            // row within 16x16 tile (A/B operand)
    const int fk = (lane >> 4) * 8;      // k offset within BK

    f32x4 acc[4][4] = {};

    for (int kt = 0; kt < 64; ++kt) {
        const unsigned short* Aseg = (kt < 32) ? Ah : Ax;
        const unsigned short* Bseg = (kt < 32) ? Bh : Bx;
        const int kk = (kt & 31) * 32;

        const unsigned short* ga0 = Aseg + gaRow + kk + stColE;
        const unsigned short* gb0 = Bseg + gbRow + kk + stColE;
        // issue 0: rows 0..63 ; issue 1: rows 64..127 (global stride 64*KH)
        __builtin_amdgcn_global_load_lds(
            (const __attribute__((address_space(1))) void*)ga0,
            (__attribute__((address_space(3))) void*)(As + wave * 512), 16, 0, 0);
        __builtin_amdgcn_global_load_lds(
            (const __attribute__((address_space(1))) void*)(ga0 + 64 * KH),
            (__attribute__((address_space(3))) void*)(As + 2048 + wave * 512), 16, 0, 0);
        __builtin_amdgcn_global_load_lds(
            (const __attribute__((address_space(1))) void*)gb0,
            (__attribute__((address_space(3))) void*)(Bs + wave * 512), 16, 0, 0);
        __builtin_amdgcn_global_load_lds(
            (const __attribute__((address_space(1))) void*)(gb0 + 64 * KH),
            (__attribute__((address_space(3))) void*)(Bs + 2048 + wave * 512), 16, 0, 0);

        __syncthreads();   // drains vmcnt before barrier

        bf16x8 a[4], b[4];
        #pragma unroll
        for (int i = 0; i < 4; ++i)
            a[i] = *(const bf16x8*)(As + (mBase + i * 16 + fr) * 32 + fk);
        #pragma unroll
        for (int j = 0; j < 4; ++j)
            b[j] = *(const bf16x8*)(Bs + (nBase + j * 16 + fr) * 32 + fk);

        #pragma unroll
        for (int i = 0; i < 4; ++i)
            #pragma unroll
            for (int j = 0; j < 4; ++j)
                acc[i][j] = __builtin_amdgcn_mfma_f32_16x16x32_bf16(a[i], b[j], acc[i][j], 0, 0, 0);

        __syncthreads();   // before next staging overwrite
    }

    // epilogue: C/D layout col = lane&15, row = (lane>>4)*4 + reg
    const int col0 = tileN * 128 + nBase + (lane & 15);
    const int row0 = tileM * 128 + mBase + (lane >> 4) * 4;
    #pragma unroll
    for (int i = 0; i < 4; ++i)
        #pragma unroll
        for (int j = 0; j < 4; ++j)
            #pragma unroll
            for (int r = 0; r < 4; ++r)
                C[(size_t)(row0 + i * 16 + r) * NOUT + (col0 + j * 16)] = f2bf(acc[i][j][r]);
}

// --------------------------------------------------------------- epilogue ---
__global__ void lstm_epilogue(const unsigned short* __restrict__ ifgo,
                              const float* __restrict__ bh,
                              const float* __restrict__ c,
                              float* __restrict__ out) {
    int tid = blockIdx.x * 256 + threadIdx.x;   // 0..4M-1
    int b = tid >> 10, j = tid & 1023;
    const unsigned short* row = ifgo + (size_t)b * NOUT;
    float iv = bf2f(row[j])        + bh[j];
    float fv = bf2f(row[j + 1024]) + bh[j + 1024];
    float gv = bf2f(row[j + 2048]) + bh[j + 2048];
    float ov = bf2f(row[j + 3072]) + bh[j + 3072];
    iv = 1.f / (1.f + __expf(-iv));
    fv = 1.f / (1.f + __expf(-fv));
    ov = 1.f / (1.f + __expf(-ov));
    gv = tanhf(gv);
    float cn = fv * c[tid] + iv * gv;
    float hn = ov * tanhf(cn);
    out[tid] = hn;
    out[ARR_ELEMS + tid] = cn;
}

// ----------------------------------------------------------------- launch ---
extern "C" void kernel_launch(void* const* d_in, const int* in_sizes, int n_in,
                              void* d_out, int out_size, void* d_ws, size_t ws_size,
                              hipStream_t stream) {
    const float* x  = (const float*)d_in[0];
    const float* h  = (const float*)d_in[1];
    const float* c  = (const float*)d_in[2];
    const float* Wh = (const float*)d_in[3];
    const float* bh = (const float*)d_in[4];
    const float* Wx = (const float*)d_in[5];
    float* out = (float*)d_out;

    unsigned short* ws   = (unsigned short*)d_ws;
    unsigned short* Ahb  = ws;                      // h  bf16, 4M elems
    unsigned short* Axb  = ws + 1 * (size_t)ARR_ELEMS;
    unsigned short* Whb  = ws + 2 * (size_t)ARR_ELEMS;
    unsigned short* Wxb  = ws + 3 * (size_t)ARR_ELEMS;
    unsigned short* ifgo = ws + 4 * (size_t)ARR_ELEMS;  // 16M elems bf16

    convert_kernel<<<16384, 256, 0, stream>>>(h, x, Wh, Wx, ws);
    dim3 grid(NOUT / 128, NB / 128);
    gemm_kernel<<<grid, 256, 0, stream>>>(Ahb, Axb, Whb, Wxb, ifgo);
    lstm_epilogue<<<16384, 256, 0, stream>>>(ifgo, bh, c, out);
}

// Round 2
// 216.641 us; speedup vs baseline: 1.0293x; 1.0293x over previous
//
#include <hip/hip_runtime.h>
#include <cstdint>
#include <cstddef>

// LSTM cell: B=4096, IN=1024, H=1024
//   ifgo = h @ Wh^T + bh + x @ Wx^T    [4096 x 4096]
//   i,f,g,o = split(ifgo); c' = sig(f)*c + sig(i)*tanh(g); h' = sig(o)*tanh(c')
//
// Pipeline (2 dispatches):
//   1. convert: fp32->bf16; W rows PERMUTED so each wave's 64 output columns
//      hold all 4 gates of 16 consecutive j:  p = (j>>4)*64 + gate*16 + (j&15)
//   2. gemm: m97-structure bf16 MFMA (128x128 tile, BK=32, global_load_lds
//      width=16) with FUSED gate epilogue writing h_next/c_next directly.

#define NB   4096      // batch
#define KH   1024      // H (== IN)
#define NOUT 4096      // 4H
#define ARR_ELEMS 4194304  // 4096*1024

typedef __bf16 bf16x8 __attribute__((ext_vector_type(8)));
typedef float  f32x4  __attribute__((ext_vector_type(4)));

__device__ inline unsigned short f2bf(float f) {
    union { float f; unsigned int u; } v; v.f = f;
    unsigned int u = v.u;
    u += 0x7FFFu + ((u >> 16) & 1u);   // RNE
    return (unsigned short)(u >> 16);
}

__device__ inline float sigmoidf(float v) { return 1.f / (1.f + __expf(-v)); }

// ---------------------------------------------------------------- convert ---
// dst layout (bf16): [h | x | Wh' | Wx'], each ARR_ELEMS elements.
// Wh'/Wx' have rows permuted: logical row L (gate g = L>>10, j = L&1023)
// lands at physical row p = ((j>>4)<<6) | (g<<4) | (j&15).
__global__ void convert_kernel(const float* __restrict__ h, const float* __restrict__ x,
                               const float* __restrict__ Wh, const float* __restrict__ Wx,
                               unsigned short* __restrict__ dst) {
    int idx = blockIdx.x * 256 + threadIdx.x;       // 0 .. 4M-1, 4 floats each
    int arr = idx >> 20;                            // 2^20 float4-chunks per array
    int off = (idx & 0xFFFFF) << 2;                 // element offset within array
    const float* src = (arr == 0) ? h : (arr == 1) ? x : (arr == 2) ? Wh : Wx;
    float4 v = *(const float4*)(src + off);
    unsigned int lo = (unsigned int)f2bf(v.x) | ((unsigned int)f2bf(v.y) << 16);
    unsigned int hi = (unsigned int)f2bf(v.z) | ((unsigned int)f2bf(v.w) << 16);
    uint2 packed; packed.x = lo; packed.y = hi;

    int dstOff = off;
    if (arr >= 2) {                                 // permute W rows
        int L   = off >> 10;                        // logical row
        int col = off & 1023;
        int g = L >> 10, j = L & 1023;
        int p = ((j >> 4) << 6) | (g << 4) | (j & 15);
        dstOff = (p << 10) | col;
    }
    *(uint2*)(dst + (size_t)arr * ARR_ELEMS + dstOff) = packed;
}

// ------------------------------------------------------------------- gemm ---
// ifgo_tile = A_cat[4096x2048] . W_cat'^T on a 128x128 tile, then fused gates.
// 256 threads (4 waves), each wave 64x64 via 4x4 MFMA 16x16x32 bf16.
__global__ void gemm_kernel(const unsigned short* __restrict__ Ah,
                            const unsigned short* __restrict__ Ax,
                            const unsigned short* __restrict__ Bh,
                            const unsigned short* __restrict__ Bx,
                            const float* __restrict__ bh,
                            const float* __restrict__ c,
                            float* __restrict__ out) {
    __shared__ __align__(16) unsigned short As[128 * 32];
    __shared__ __align__(16) unsigned short Bs[128 * 32];

    const int tid  = threadIdx.x;
    const int wave = tid >> 6;
    const int lane = tid & 63;
    const int tileN = blockIdx.x;   // 0..31  (output cols / 128)
    const int tileM = blockIdx.y;   // 0..31  (output rows / 128)

    // staging addressing: lane writes LDS at waveBase + lane*16B (wave-uniform rule)
    const int stRow  = wave * 16 + (lane >> 2);   // 0..63 for issue 0
    const int stColE = (lane & 3) * 8;            // element offset in K
    const size_t gaRow = (size_t)(tileM * 128 + stRow) * KH;
    const size_t gbRow = (size_t)(tileN * 128 + stRow) * KH;

    // compute-side fragment addressing
    const int mBase = (wave >> 1) * 64;
    const int nBase = (wave & 1) * 64;
    const int fr = lane & 15;            // row within 16x16 tile (A/B operand)
    const int fk = (lane >> 4) * 8;      // k offset within BK

    f32x4 acc[4][4] = {};

    for (int kt = 0; kt < 64; ++kt) {
        const unsigned short* Aseg = (kt < 32) ? Ah : Ax;
        const unsigned short* Bseg = (kt < 32) ? Bh : Bx;
        const int kk = (kt & 31) * 32;

        const unsigned short* ga0 = Aseg + gaRow + kk + stColE;
        const unsigned short* gb0 = Bseg + gbRow + kk + stColE;
        __builtin_amdgcn_global_load_lds(
            (const __attribute__((address_space(1))) void*)ga0,
            (__attribute__((address_space(3))) void*)(As + wave * 512), 16, 0, 0);
        __builtin_amdgcn_global_load_lds(
            (const __attribute__((address_space(1))) void*)(ga0 + 64 * KH),
            (__attribute__((address_space(3))) void*)(As + 2048 + wave * 512), 16, 0, 0);
        __builtin_amdgcn_global_load_lds(
            (const __attribute__((address_space(1))) void*)gb0,
            (__attribute__((address_space(3))) void*)(Bs + wave * 512), 16, 0, 0);
        __builtin_amdgcn_global_load_lds(
            (const __attribute__((address_space(1))) void*)(gb0 + 64 * KH),
            (__attribute__((address_space(3))) void*)(Bs + 2048 + wave * 512), 16, 0, 0);

        __syncthreads();

        bf16x8 a[4], b[4];
        #pragma unroll
        for (int i = 0; i < 4; ++i)
            a[i] = *(const bf16x8*)(As + (mBase + i * 16 + fr) * 32 + fk);
        #pragma unroll
        for (int j = 0; j < 4; ++j)
            b[j] = *(const bf16x8*)(Bs + (nBase + j * 16 + fr) * 32 + fk);

        #pragma unroll
        for (int i = 0; i < 4; ++i)
            #pragma unroll
            for (int j = 0; j < 4; ++j)
                acc[i][j] = __builtin_amdgcn_mfma_f32_16x16x32_bf16(a[i], b[j], acc[i][j], 0, 0, 0);

        __syncthreads();
    }

    // ---- fused LSTM gate epilogue -------------------------------------
    // Physical col of acc[i][k][r] = tileN*128 + nBase + 16k + (lane&15);
    // with the W-row permutation: gate = k, logical j = 16*q + (lane&15),
    // q = (tileN*128 + nBase)/64 = tileN*2 + (wave&1).
    const int j = ((tileN * 2 + (wave & 1)) << 4) | (lane & 15);
    const float bi = bh[j];
    const float bf = bh[j + 1024];
    const float bg = bh[j + 2048];
    const float bo = bh[j + 3072];

    const int row0 = tileM * 128 + mBase + (lane >> 4) * 4;
    #pragma unroll
    for (int i = 0; i < 4; ++i) {
        #pragma unroll
        for (int r = 0; r < 4; ++r) {
            const int m = row0 + i * 16 + r;
            const size_t idx = (size_t)m * KH + j;
            float iv = sigmoidf(acc[i][0][r] + bi);
            float fv = sigmoidf(acc[i][1][r] + bf);
            float gv = tanhf(acc[i][2][r] + bg);
            float ov = sigmoidf(acc[i][3][r] + bo);
            float cn = fv * c[idx] + iv * gv;
            float hn = ov * tanhf(cn);
            out[idx] = hn;
            out[(size_t)ARR_ELEMS + idx] = cn;
        }
    }
}

// ----------------------------------------------------------------- launch ---
extern "C" void kernel_launch(void* const* d_in, const int* in_sizes, int n_in,
                              void* d_out, int out_size, void* d_ws, size_t ws_size,
                              hipStream_t stream) {
    const float* x  = (const float*)d_in[0];
    const float* h  = (const float*)d_in[1];
    const float* c  = (const float*)d_in[2];
    const float* Wh = (const float*)d_in[3];
    const float* bh = (const float*)d_in[4];
    const float* Wx = (const float*)d_in[5];
    float* out = (float*)d_out;

    unsigned short* ws  = (unsigned short*)d_ws;
    unsigned short* Ahb = ws;                           // h  bf16
    unsigned short* Axb = ws + 1 * (size_t)ARR_ELEMS;   // x  bf16
    unsigned short* Whb = ws + 2 * (size_t)ARR_ELEMS;   // Wh bf16 (row-permuted)
    unsigned short* Wxb = ws + 3 * (size_t)ARR_ELEMS;   // Wx bf16 (row-permuted)

    convert_kernel<<<16384, 256, 0, stream>>>(h, x, Wh, Wx, ws);
    dim3 grid(NOUT / 128, NB / 128);
    gemm_kernel<<<grid, 256, 0, stream>>>(Ahb, Axb, Whb, Wxb, bh, c, out);
}

// Round 3
// 205.952 us; speedup vs baseline: 1.0827x; 1.0519x over previous
//
#include <hip/hip_runtime.h>
#include <cstdint>
#include <cstddef>

// LSTM cell: B=4096, IN=1024, H=1024
//   ifgo = h @ Wh^T + bh + x @ Wx^T    [4096 x 4096]
//   i,f,g,o = split(ifgo); c' = sig(f)*c + sig(i)*tanh(g); h' = sig(o)*tanh(c')
//
// Pipeline (2 dispatches):
//   1. convert: fp32->bf16; W rows PERMUTED so each wave's 64 output columns
//      hold all 4 gates of 16 consecutive j:  p = (j>>4)*64 + gate*16 + (j&15)
//   2. gemm: m97-structure bf16 MFMA (128x128 tile, BK=32, global_load_lds
//      width=16) with FUSED fast-math gate epilogue writing h_next/c_next.

#define NB   4096      // batch
#define KH   1024      // H (== IN)
#define NOUT 4096      // 4H
#define ARR_ELEMS 4194304  // 4096*1024

typedef __bf16 bf16x8 __attribute__((ext_vector_type(8)));
typedef float  f32x4  __attribute__((ext_vector_type(4)));

__device__ inline unsigned short f2bf(float f) {
    union { float f; unsigned int u; } v; v.f = f;
    unsigned int u = v.u;
    u += 0x7FFFu + ((u >> 16) & 1u);   // RNE
    return (unsigned short)(u >> 16);
}

// fast gates: v_exp_f32 + v_rcp_f32, no branches (libm tanhf is branchy/slow)
__device__ inline float fsig(float v)  { return __builtin_amdgcn_rcpf(1.f + __expf(-v)); }
__device__ inline float ftanh(float v) { return 1.f - 2.f * __builtin_amdgcn_rcpf(1.f + __expf(2.f * v)); }

// ---------------------------------------------------------------- convert ---
// dst layout (bf16): [h | x | Wh' | Wx'], each ARR_ELEMS elements.
// Wh'/Wx' have rows permuted: logical row L (gate g = L>>10, j = L&1023)
// lands at physical row p = ((j>>4)<<6) | (g<<4) | (j&15).
__global__ void convert_kernel(const float* __restrict__ h, const float* __restrict__ x,
                               const float* __restrict__ Wh, const float* __restrict__ Wx,
                               unsigned short* __restrict__ dst) {
    int idx = blockIdx.x * 256 + threadIdx.x;       // 0 .. 4M-1, 4 floats each
    int arr = idx >> 20;                            // 2^20 float4-chunks per array
    int off = (idx & 0xFFFFF) << 2;                 // element offset within array
    const float* src = (arr == 0) ? h : (arr == 1) ? x : (arr == 2) ? Wh : Wx;
    float4 v = *(const float4*)(src + off);
    unsigned int lo = (unsigned int)f2bf(v.x) | ((unsigned int)f2bf(v.y) << 16);
    unsigned int hi = (unsigned int)f2bf(v.z) | ((unsigned int)f2bf(v.w) << 16);
    uint2 packed; packed.x = lo; packed.y = hi;

    int dstOff = off;
    if (arr >= 2) {                                 // permute W rows
        int L   = off >> 10;                        // logical row
        int col = off & 1023;
        int g = L >> 10, j = L & 1023;
        int p = ((j >> 4) << 6) | (g << 4) | (j & 15);
        dstOff = (p << 10) | col;
    }
    *(uint2*)(dst + (size_t)arr * ARR_ELEMS + dstOff) = packed;
}

// ------------------------------------------------------------------- gemm ---
// ifgo_tile = A_cat[4096x2048] . W_cat'^T on a 128x128 tile, then fused gates.
// 256 threads (4 waves), each wave 64x64 via 4x4 MFMA 16x16x32 bf16.
__global__ void gemm_kernel(const unsigned short* __restrict__ Ah,
                            const unsigned short* __restrict__ Ax,
                            const unsigned short* __restrict__ Bh,
                            const unsigned short* __restrict__ Bx,
                            const float* __restrict__ bh,
                            const float* __restrict__ c,
                            float* __restrict__ out) {
    __shared__ __align__(16) unsigned short As[128 * 32];
    __shared__ __align__(16) unsigned short Bs[128 * 32];

    const int tid  = threadIdx.x;
    const int wave = tid >> 6;
    const int lane = tid & 63;
    const int tileN = blockIdx.x;   // 0..31  (output cols / 128)
    const int tileM = blockIdx.y;   // 0..31  (output rows / 128)

    // staging addressing: lane writes LDS at waveBase + lane*16B (wave-uniform rule)
    const int stRow  = wave * 16 + (lane >> 2);   // 0..63 for issue 0
    const int stColE = (lane & 3) * 8;            // element offset in K
    const size_t gaRow = (size_t)(tileM * 128 + stRow) * KH;
    const size_t gbRow = (size_t)(tileN * 128 + stRow) * KH;

    // compute-side fragment addressing
    const int mBase = (wave >> 1) * 64;
    const int nBase = (wave & 1) * 64;
    const int fr = lane & 15;            // row within 16x16 tile (A/B operand)
    const int fk = (lane >> 4) * 8;      // k offset within BK

    f32x4 acc[4][4] = {};

    for (int kt = 0; kt < 64; ++kt) {
        const unsigned short* Aseg = (kt < 32) ? Ah : Ax;
        const unsigned short* Bseg = (kt < 32) ? Bh : Bx;
        const int kk = (kt & 31) * 32;

        const unsigned short* ga0 = Aseg + gaRow + kk + stColE;
        const unsigned short* gb0 = Bseg + gbRow + kk + stColE;
        __builtin_amdgcn_global_load_lds(
            (const __attribute__((address_space(1))) void*)ga0,
            (__attribute__((address_space(3))) void*)(As + wave * 512), 16, 0, 0);
        __builtin_amdgcn_global_load_lds(
            (const __attribute__((address_space(1))) void*)(ga0 + 64 * KH),
            (__attribute__((address_space(3))) void*)(As + 2048 + wave * 512), 16, 0, 0);
        __builtin_amdgcn_global_load_lds(
            (const __attribute__((address_space(1))) void*)gb0,
            (__attribute__((address_space(3))) void*)(Bs + wave * 512), 16, 0, 0);
        __builtin_amdgcn_global_load_lds(
            (const __attribute__((address_space(1))) void*)(gb0 + 64 * KH),
            (__attribute__((address_space(3))) void*)(Bs + 2048 + wave * 512), 16, 0, 0);

        __syncthreads();

        bf16x8 a[4], b[4];
        #pragma unroll
        for (int i = 0; i < 4; ++i)
            a[i] = *(const bf16x8*)(As + (mBase + i * 16 + fr) * 32 + fk);
        #pragma unroll
        for (int j = 0; j < 4; ++j)
            b[j] = *(const bf16x8*)(Bs + (nBase + j * 16 + fr) * 32 + fk);

        #pragma unroll
        for (int i = 0; i < 4; ++i)
            #pragma unroll
            for (int j = 0; j < 4; ++j)
                acc[i][j] = __builtin_amdgcn_mfma_f32_16x16x32_bf16(a[i], b[j], acc[i][j], 0, 0, 0);

        __syncthreads();
    }

    // ---- fused LSTM gate epilogue -------------------------------------
    // Physical col of acc[i][k][r] = tileN*128 + nBase + 16k + (lane&15);
    // with the W-row permutation: gate = k, logical j = 16*q + (lane&15),
    // q = (tileN*128 + nBase)/64 = tileN*2 + (wave&1).
    const int j = ((tileN * 2 + (wave & 1)) << 4) | (lane & 15);
    const float bi = bh[j];
    const float bf = bh[j + 1024];
    const float bg = bh[j + 2048];
    const float bo = bh[j + 3072];

    const int row0 = tileM * 128 + mBase + (lane >> 4) * 4;

    // batch all c loads first: one latency exposure, not 16 serialized ones
    float cv[4][4];
    #pragma unroll
    for (int i = 0; i < 4; ++i)
        #pragma unroll
        for (int r = 0; r < 4; ++r)
            cv[i][r] = c[(size_t)(row0 + i * 16 + r) * KH + j];

    #pragma unroll
    for (int i = 0; i < 4; ++i) {
        #pragma unroll
        for (int r = 0; r < 4; ++r) {
            const size_t idx = (size_t)(row0 + i * 16 + r) * KH + j;
            float iv = fsig(acc[i][0][r] + bi);
            float fv = fsig(acc[i][1][r] + bf);
            float gv = ftanh(acc[i][2][r] + bg);
            float ov = fsig(acc[i][3][r] + bo);
            float cn = fv * cv[i][r] + iv * gv;
            float hn = ov * ftanh(cn);
            out[idx] = hn;
            out[(size_t)ARR_ELEMS + idx] = cn;
        }
    }
}

// ----------------------------------------------------------------- launch ---
extern "C" void kernel_launch(void* const* d_in, const int* in_sizes, int n_in,
                              void* d_out, int out_size, void* d_ws, size_t ws_size,
                              hipStream_t stream) {
    const float* x  = (const float*)d_in[0];
    const float* h  = (const float*)d_in[1];
    const float* c  = (const float*)d_in[2];
    const float* Wh = (const float*)d_in[3];
    const float* bh = (const float*)d_in[4];
    const float* Wx = (const float*)d_in[5];
    float* out = (float*)d_out;

    unsigned short* ws  = (unsigned short*)d_ws;
    unsigned short* Ahb = ws;                           // h  bf16
    unsigned short* Axb = ws + 1 * (size_t)ARR_ELEMS;   // x  bf16
    unsigned short* Whb = ws + 2 * (size_t)ARR_ELEMS;   // Wh bf16 (row-permuted)
    unsigned short* Wxb = ws + 3 * (size_t)ARR_ELEMS;   // Wx bf16 (row-permuted)

    convert_kernel<<<16384, 256, 0, stream>>>(h, x, Wh, Wx, ws);
    dim3 grid(NOUT / 128, NB / 128);
    gemm_kernel<<<grid, 256, 0, stream>>>(Ahb, Axb, Whb, Wxb, bh, c, out);
}